// Round 11
// baseline (1528.891 us; speedup 1.0000x reference)
//
#include <hip/hip_runtime.h>
#include <math.h>

#define E_ 4
#define B_ 16
#define S_ 224
#define P_ 16
#define D_ 384
#define H_ 6
#define HD_ 64
#define L_ 12
#define FF_ 1536
#define NC_ 10
#define NP_ 196
#define T_ 197
#define GATE_K (3 * S_ * S_)  // 150528
#define GSPLIT 32
#define GCHUNK (GATE_K / GSPLIT)  // 4704

typedef __attribute__((ext_vector_type(8))) short bf16x8;
typedef __attribute__((ext_vector_type(4))) float f32x4;

__device__ inline unsigned short f2bf(float f) {
  union { float f; unsigned u; } v; v.f = f;
  unsigned r = v.u + 0x7FFFu + ((v.u >> 16) & 1u);  // RNE
  return (unsigned short)(r >> 16);
}

// ---------------- gate phase 1: partial dot products ----------------
__global__ __launch_bounds__(256) void gate_partial(const float* __restrict__ x,
                                                    const float* __restrict__ gw,
                                                    float4* __restrict__ part) {
  int b = blockIdx.x, s = blockIdx.y, tid = threadIdx.x;
  const float* xb = x + (size_t)b * GATE_K;
  const float4* gw4 = (const float4*)gw;
  int i0 = s * GCHUNK, i1 = i0 + GCHUNK;
  float4 acc = make_float4(0.f, 0.f, 0.f, 0.f);
  for (int i = i0 + tid; i < i1; i += 256) {
    float xv = xb[i];
    float4 w = gw4[i];
    acc.x += xv * w.x; acc.y += xv * w.y; acc.z += xv * w.z; acc.w += xv * w.w;
  }
  __shared__ float4 red[256];
  red[tid] = acc;
  __syncthreads();
  for (int off = 128; off > 0; off >>= 1) {
    if (tid < off) {
      float4 o = red[tid + off];
      red[tid].x += o.x; red[tid].y += o.y; red[tid].z += o.z; red[tid].w += o.w;
    }
    __syncthreads();
  }
  if (tid == 0) part[b * GSPLIT + s] = red[0];
}

// ---------------- gate phase 2: reduce + argmax ----------------
__global__ void gate_reduce(const float4* __restrict__ part, const float* __restrict__ gb,
                            int* __restrict__ idx) {
  int b = blockIdx.x;
  int lane = threadIdx.x;  // 64
  float4 a = make_float4(0.f, 0.f, 0.f, 0.f);
  if (lane < GSPLIT) a = part[b * GSPLIT + lane];
#pragma unroll
  for (int off = 1; off < 64; off <<= 1) {
    a.x += __shfl_xor(a.x, off);
    a.y += __shfl_xor(a.y, off);
    a.z += __shfl_xor(a.z, off);
    a.w += __shfl_xor(a.w, off);
  }
  if (lane == 0) {
    float v[4] = {a.x + gb[0], a.y + gb[1], a.z + gb[2], a.w + gb[3]};
    int best = 0;
    for (int e = 1; e < 4; ++e) if (v[e] > v[best]) best = e;
    idx[b] = best;
  }
}

// ---------------- cls row ----------------
__global__ void cls_kernel(const float* __restrict__ cls, const float* __restrict__ pos,
                           const int* __restrict__ idx, float* __restrict__ t) {
  int b = blockIdx.x;
  int d = threadIdx.x;
  int e = idx[b];
  t[((size_t)b * T_) * D_ + d] = cls[e * D_ + d] + pos[((size_t)e * T_) * D_ + d];
}

// ---------------- im2col: x fp32 -> xpb bf16 [B][196][768] ----------------
__global__ __launch_bounds__(256) void im2col_kernel(const float* __restrict__ x,
                                                     unsigned short* __restrict__ xpb) {
  int m = blockIdx.x, b = blockIdx.y, tid = threadIdx.x;
  int pr = m / 14, pc = m - pr * 14;
#pragma unroll
  for (int i = 0; i < 3; ++i) {
    int j = tid + i * 256;
    int c = j >> 8, y = (j >> 4) & 15, xx = j & 15;
    float v = x[(((size_t)b * 3 + c) * S_ + pr * 16 + y) * S_ + pc * 16 + xx];
    xpb[((size_t)b * NP_ + m) * 768 + j] = f2bf(v);
  }
}

// ---------------- transpose tile helper: [k=128][n=64], XOR-swizzled ----------------
// 256B coalesced fp32 reads AND 2x128B bf16 row writes (256B per output row).
__device__ inline void trans_tile_128(const float* __restrict__ src, int srcN,
                                      unsigned short* __restrict__ dst, int dstK,
                                      int k0, int n0, int tid) {
  __shared__ unsigned short tile[128][64];
  int rr = tid >> 4, c4 = (tid & 15) * 4;
#pragma unroll
  for (int p = 0; p < 8; ++p) {
    int row = p * 16 + rr;
    float4 v = *(const float4*)(src + (size_t)(k0 + row) * srcN + n0 + c4);
    ushort4 o;
    o.x = f2bf(v.x); o.y = f2bf(v.y); o.z = f2bf(v.z); o.w = f2bf(v.w);
    *(ushort4*)&tile[row][c4 ^ (row & 56)] = o;
  }
  __syncthreads();
  int n = tid >> 3, k8 = (tid & 7) * 8;
#pragma unroll
  for (int pn = 0; pn < 2; ++pn) {
    int nn = pn * 32 + n;
#pragma unroll
    for (int pk = 0; pk < 2; ++pk) {
      int kk = pk * 64 + k8;
      union { unsigned short us[8]; uint4 u4; } o;
#pragma unroll
      for (int j = 0; j < 8; ++j) {
        int row = kk + j;
        o.us[j] = tile[row][nn ^ (row & 56)];
      }
      *(uint4*)(dst + (size_t)(n0 + nn) * dstK + k0 + kk) = o.u4;
    }
  }
}

// ---------------- patch_w transpose: [E][768][384] -> [E][384][768] bf16 ----------------
__global__ __launch_bounds__(256) void ptrans_kernel(const float* __restrict__ pw,
                                                     unsigned short* __restrict__ tpw) {
  int e = blockIdx.y;
  int r = blockIdx.x;  // 36 tiles: 6 k-tiles x 6 n-tiles
  const int K = 768, N = 384;
  int kt = r / 6, nt = r - kt * 6;
  trans_tile_128(pw + (size_t)e * K * N, N, tpw + (size_t)e * N * K, K,
                 kt * 128, nt * 64, threadIdx.x);
}

// ---------------- weight transpose: W[K][N] fp32 -> WT[slot][e][N][K] bf16 ----------------
__global__ __launch_bounds__(256) void wtrans_kernel(
    const float* __restrict__ qw, const float* __restrict__ pw,
    const float* __restrict__ f1, const float* __restrict__ f2,
    unsigned short* __restrict__ tq, unsigned short* __restrict__ tp,
    unsigned short* __restrict__ t1, unsigned short* __restrict__ t2, int lsrc_base) {
  int e = blockIdx.y;
  int slot = blockIdx.z;
  int l = lsrc_base + slot;
  int r = blockIdx.x;  // 0..215 ([128k][64n] tiles)
  const float* src; unsigned short* dst; int K, N, kt, nt;
  if (r < 54) {         // qkv: 384x1152 -> 3x18
    K = 384; N = 1152;
    src = qw + (size_t)(e * L_ + l) * K * N; dst = tq + (size_t)(slot * E_ + e) * K * N;
    kt = r / 18; nt = r % 18;
  } else if (r < 72) {  // proj: 384x384 -> 3x6
    r -= 54; K = 384; N = 384;
    src = pw + (size_t)(e * L_ + l) * K * N; dst = tp + (size_t)(slot * E_ + e) * K * N;
    kt = r / 6; nt = r % 6;
  } else if (r < 144) { // fc1: 384x1536 -> 3x24
    r -= 72; K = 384; N = 1536;
    src = f1 + (size_t)(e * L_ + l) * K * N; dst = t1 + (size_t)(slot * E_ + e) * K * N;
    kt = r / 24; nt = r % 24;
  } else {              // fc2: 1536x384 -> 12x6
    r -= 144; K = 1536; N = 384;
    src = f2 + (size_t)(e * L_ + l) * K * N; dst = t2 + (size_t)(slot * E_ + e) * K * N;
    kt = r / 6; nt = r % 6;
  }
  trans_tile_128(src, N, dst, K, kt * 128, nt * 64, threadIdx.x);
}

// ---------------- layernorm -> bf16 out ----------------
__global__ void ln_kernel(const float* __restrict__ in, unsigned short* __restrict__ out,
                          const float* __restrict__ w, const float* __restrict__ bc,
                          const int* __restrict__ idx, int l) {
  int b = blockIdx.y;
  int row = blockIdx.x * 4 + (threadIdx.x >> 6);
  if (row >= T_) return;
  int lane = threadIdx.x & 63;
  int e = idx[b];
  const float* rp = in + ((size_t)b * T_ + row) * D_;
  float v[6];
  float s = 0.f;
#pragma unroll
  for (int j = 0; j < 6; ++j) { v[j] = rp[lane + j * 64]; s += v[j]; }
#pragma unroll
  for (int off = 1; off < 64; off <<= 1) s += __shfl_xor(s, off);
  float mean = s * (1.f / 384.f);
  float sq = 0.f;
#pragma unroll
  for (int j = 0; j < 6; ++j) { float dd = v[j] - mean; sq += dd * dd; }
#pragma unroll
  for (int off = 1; off < 64; off <<= 1) sq += __shfl_xor(sq, off);
  float rs = rsqrtf(sq * (1.f / 384.f) + 1e-6f);
  const float* wrow = w + ((size_t)e * L_ + l) * D_;
  const float* brow = bc + ((size_t)e * L_ + l) * D_;
  unsigned short* op = out + ((size_t)b * T_ + row) * D_;
#pragma unroll
  for (int j = 0; j < 6; ++j) {
    int d = lane + j * 64;
    op[d] = f2bf((v[j] - mean) * rs * wrow[d] + brow[d]);
  }
}

// ---------------- MFMA bf16 GEMM, BMxBN tile, BK=64, register prefetch ----------------
// 4 waves as 2x2; wave covers (BM/2)x(BN/2).
// EPI: 0 fp32 store, 1 fp32 residual add, 2 GELU->bf16, 3 bf16 store,
//      4 patch: fp32 t store at row+1 with pos add.
template <int EPI, int BM, int BN>
__global__ __launch_bounds__(256, 4) void gemm_mfma(
    const unsigned short* __restrict__ A, const unsigned short* __restrict__ WT,
    const float* __restrict__ bias, void* __restrict__ Out,
    const int* __restrict__ idx, int l, int K, int N, int M, size_t asb,
    int bstride, const float* __restrict__ pos) {
  constexpr int MF = BM / 32;   // m-frags per wave
  constexpr int NF = BN / 32;   // n-frags per wave
  constexpr int AL = BM / 32;   // uint4 loads per thread for A tile
  constexpr int BL = BN / 32;
  int b = blockIdx.z;
  int e = idx[b];
  int n0 = blockIdx.x * BN, m0 = blockIdx.y * BM;
  int tid = threadIdx.x;
  const unsigned short* Ab = A + (size_t)b * asb;
  const unsigned short* Wb = WT + (size_t)e * N * K;
  __shared__ unsigned short Asl[8][BM][8];
  __shared__ unsigned short Bsl[8][BN][8];
  f32x4 acc[MF][NF];
#pragma unroll
  for (int i = 0; i < MF; ++i)
#pragma unroll
    for (int j = 0; j < NF; ++j) acc[i][j] = (f32x4){0.f, 0.f, 0.f, 0.f};
  int wid = tid >> 6, lane = tid & 63;
  int wm = (wid >> 1) * (BM / 2), wn = (wid & 1) * (BN / 2);
  int lrow = lane & 15, lk = lane >> 4;
  int sr = tid >> 3, skq = tid & 7;  // staging: row group, k-octet

  uint4 aC[AL], bC[BL], aN[AL], bN[BL];
#pragma unroll
  for (int j = 0; j < AL; ++j) {
    int row = m0 + sr + j * 32;
    aC[j] = (row < M) ? *(const uint4*)(Ab + (size_t)row * K + skq * 8)
                      : make_uint4(0, 0, 0, 0);
    aN[j] = make_uint4(0, 0, 0, 0);
  }
#pragma unroll
  for (int j = 0; j < BL; ++j) {
    bC[j] = *(const uint4*)(Wb + (size_t)(n0 + sr + j * 32) * K + skq * 8);
    bN[j] = make_uint4(0, 0, 0, 0);
  }
  for (int k0 = 0; k0 < K; k0 += 64) {
    __syncthreads();
#pragma unroll
    for (int j = 0; j < AL; ++j) *(uint4*)&Asl[skq][sr + j * 32][0] = aC[j];
#pragma unroll
    for (int j = 0; j < BL; ++j) *(uint4*)&Bsl[skq][sr + j * 32][0] = bC[j];
    __syncthreads();
    if (k0 + 64 < K) {  // issue next-step loads before the MFMAs
#pragma unroll
      for (int j = 0; j < AL; ++j) {
        int row = m0 + sr + j * 32;
        if (row < M) aN[j] = *(const uint4*)(Ab + (size_t)row * K + k0 + 64 + skq * 8);
      }
#pragma unroll
      for (int j = 0; j < BL; ++j)
        bN[j] = *(const uint4*)(Wb + (size_t)(n0 + sr + j * 32) * K + k0 + 64 + skq * 8);
    }
#pragma unroll
    for (int ks = 0; ks < 2; ++ks) {
      bf16x8 bb[NF];
#pragma unroll
      for (int fn = 0; fn < NF; ++fn)
        bb[fn] = *(const bf16x8*)&Bsl[ks * 4 + lk][wn + fn * 16 + lrow][0];
#pragma unroll
      for (int fm = 0; fm < MF; ++fm) {
        bf16x8 aa = *(const bf16x8*)&Asl[ks * 4 + lk][wm + fm * 16 + lrow][0];
#pragma unroll
        for (int fn = 0; fn < NF; ++fn)
          acc[fm][fn] = __builtin_amdgcn_mfma_f32_16x16x32_bf16(aa, bb[fn], acc[fm][fn], 0, 0, 0);
      }
    }
#pragma unroll
    for (int j = 0; j < AL; ++j) aC[j] = aN[j];
#pragma unroll
    for (int j = 0; j < BL; ++j) bC[j] = bN[j];
  }
  const float* brow = bias + ((size_t)e * bstride + l) * N + n0;
#pragma unroll
  for (int fm = 0; fm < MF; ++fm)
#pragma unroll
    for (int fn = 0; fn < NF; ++fn) {
      int col = wn + fn * 16 + lrow;
      float bval = brow[col];
#pragma unroll
      for (int r = 0; r < 4; ++r) {
        int row = m0 + wm + fm * 16 + lk * 4 + r;
        if (row >= M) continue;
        float val = acc[fm][fn][r] + bval;
        if (EPI == 0) {
          ((float*)Out)[((size_t)b * T_ + row) * N + n0 + col] = val;
        } else if (EPI == 1) {
          float* p = (float*)Out + ((size_t)b * T_ + row) * N + n0 + col;
          *p = *p + val;
        } else if (EPI == 2) {
          val = 0.5f * val * (1.f + erff(val * 0.70710678118654752f));
          ((unsigned short*)Out)[((size_t)b * T_ + row) * N + n0 + col] = f2bf(val);
        } else if (EPI == 3) {
          ((unsigned short*)Out)[((size_t)b * T_ + row) * N + n0 + col] = f2bf(val);
        } else {  // 4: patch -> t rows 1..196 with pos
          ((float*)Out)[((size_t)b * T_ + 1 + row) * N + n0 + col] =
              val + pos[((size_t)e * T_ + 1 + row) * N + n0 + col];
        }
      }
    }
}

// ---------------- attention: MFMA bf16, 2 waves/block ----------------
__global__ __launch_bounds__(128, 2) void attn_mfma(const unsigned short* __restrict__ qkvb,
                                                    unsigned short* __restrict__ ob) {
  int b = blockIdx.z, h = blockIdx.y, qt = blockIdx.x;
  int tid = threadIdx.x;  // 128
  int w = tid >> 6, lane = tid & 63;
  int q0 = qt * 32 + w * 16;
  __shared__ unsigned short Vt[64][232];
  __shared__ unsigned short Pl[2][16][232];
  const unsigned short* base = qkvb + (size_t)b * T_ * (3 * D_) + h * HD_;

  {
    int d2 = (tid & 31) * 2;
    int kvh = tid >> 5;  // 0..3
    const unsigned short* vb = base + 2 * D_;
    for (int i = 0; i < 56; ++i) {
      int kv = kvh * 56 + i;
      int kvc = kv < T_ ? kv : T_ - 1;
      unsigned int vv = *(const unsigned int*)(vb + (size_t)kvc * (3 * D_) + d2);
      Vt[d2][kv] = (unsigned short)(vv & 0xffffu);
      Vt[d2 + 1][kv] = (unsigned short)(vv >> 16);
    }
  }

  int c16 = lane & 15, g4 = lane >> 4;

  int qrow = q0 + c16; if (qrow > T_ - 1) qrow = T_ - 1;
  bf16x8 aq[2];
#pragma unroll
  for (int ks = 0; ks < 2; ++ks)
    aq[ks] = *(const bf16x8*)(base + (size_t)qrow * (3 * D_) + ks * 32 + g4 * 8);

  f32x4 sc[14];
#pragma unroll
  for (int nf = 0; nf < 14; ++nf) sc[nf] = (f32x4){0.f, 0.f, 0.f, 0.f};
  const unsigned short* kb = base + D_;
#pragma unroll
  for (int nf = 0; nf < 14; ++nf) {
    int krow = nf * 16 + c16; if (krow > T_ - 1) krow = T_ - 1;
#pragma unroll
    for (int ks = 0; ks < 2; ++ks) {
      bf16x8 bk = *(const bf16x8*)(kb + (size_t)krow * (3 * D_) + ks * 32 + g4 * 8);
      sc[nf] = __builtin_amdgcn_mfma_f32_16x16x32_bf16(aq[ks], bk, sc[nf], 0, 0, 0);
    }
  }

  float mx[4], sm[4];
#pragma unroll
  for (int r = 0; r < 4; ++r) mx[r] = -1e30f;
#pragma unroll
  for (int nf = 0; nf < 14; ++nf) {
    bool valid = (nf * 16 + c16) < T_;
#pragma unroll
    for (int r = 0; r < 4; ++r) {
      float s = valid ? sc[nf][r] * 0.125f : -1e30f;
      sc[nf][r] = s;
      mx[r] = fmaxf(mx[r], s);
    }
  }
#pragma unroll
  for (int r = 0; r < 4; ++r) {
#pragma unroll
    for (int off = 1; off < 16; off <<= 1) mx[r] = fmaxf(mx[r], __shfl_xor(mx[r], off, 16));
    sm[r] = 0.f;
  }
#pragma unroll
  for (int nf = 0; nf < 14; ++nf)
#pragma unroll
    for (int r = 0; r < 4; ++r) {
      float p = __expf(sc[nf][r] - mx[r]);
      sc[nf][r] = p;
      sm[r] += p;
    }
#pragma unroll
  for (int r = 0; r < 4; ++r) {
#pragma unroll
    for (int off = 1; off < 16; off <<= 1) sm[r] += __shfl_xor(sm[r], off, 16);
    sm[r] = 1.f / sm[r];
  }
#pragma unroll
  for (int nf = 0; nf < 14; ++nf) {
    int col = nf * 16 + c16;
#pragma unroll
    for (int r = 0; r < 4; ++r)
      Pl[w][g4 * 4 + r][col] = f2bf(sc[nf][r] * sm[r]);
  }
  __syncthreads();

  f32x4 oacc[4];
#pragma unroll
  for (int nf = 0; nf < 4; ++nf) oacc[nf] = (f32x4){0.f, 0.f, 0.f, 0.f};
#pragma unroll
  for (int ks = 0; ks < 7; ++ks) {
    bf16x8 ap = *(const bf16x8*)&Pl[w][c16][ks * 32 + g4 * 8];
#pragma unroll
    for (int nf = 0; nf < 4; ++nf) {
      bf16x8 bv = *(const bf16x8*)&Vt[nf * 16 + c16][ks * 32 + g4 * 8];
      oacc[nf] = __builtin_amdgcn_mfma_f32_16x16x32_bf16(ap, bv, oacc[nf], 0, 0, 0);
    }
  }

#pragma unroll
  for (int nf = 0; nf < 4; ++nf) {
    int d = nf * 16 + c16;
#pragma unroll
    for (int r = 0; r < 4; ++r) {
      int q = q0 + g4 * 4 + r;
      if (q < T_)
        ob[((size_t)b * T_ + q) * D_ + h * HD_ + d] = f2bf(oacc[nf][r]);
    }
  }
}

// ---------------- final LN(row 0) + head ----------------
__global__ void head_kernel(const float* __restrict__ t, const float* __restrict__ nw,
                            const float* __restrict__ nb, const float* __restrict__ hw,
                            const float* __restrict__ hb, const int* __restrict__ idx,
                            float* __restrict__ out) {
  int b = blockIdx.x;
  int e = idx[b];
  int lane = threadIdx.x;  // 64
  const float* rp = t + (size_t)b * T_ * D_;
  float v[6];
  float s = 0.f;
#pragma unroll
  for (int j = 0; j < 6; ++j) { v[j] = rp[lane + j * 64]; s += v[j]; }
#pragma unroll
  for (int off = 1; off < 64; off <<= 1) s += __shfl_xor(s, off);
  float mean = s * (1.f / 384.f);
  float sq = 0.f;
#pragma unroll
  for (int j = 0; j < 6; ++j) { float dd = v[j] - mean; sq += dd * dd; }
#pragma unroll
  for (int off = 1; off < 64; off <<= 1) sq += __shfl_xor(sq, off);
  float rs = rsqrtf(sq * (1.f / 384.f) + 1e-6f);
  __shared__ float ln[D_];
#pragma unroll
  for (int j = 0; j < 6; ++j) {
    int d = lane + j * 64;
    ln[d] = (v[j] - mean) * rs * nw[e * D_ + d] + nb[e * D_ + d];
  }
  __syncthreads();
  if (lane < NC_) {
    float acc = hb[e * NC_ + lane];
    for (int d = 0; d < D_; ++d) acc += ln[d] * hw[((size_t)e * D_ + d) * NC_ + lane];
    out[b * NC_ + lane] = acc;
  }
}

extern "C" void kernel_launch(void* const* d_in, const int* in_sizes, int n_in,
                              void* d_out, int out_size, void* d_ws, size_t ws_size,
                              hipStream_t stream) {
  const float* x      = (const float*)d_in[0];
  const float* gate_w = (const float*)d_in[1];
  const float* gate_b = (const float*)d_in[2];
  const float* patch_w = (const float*)d_in[3];
  const float* patch_b = (const float*)d_in[4];
  const float* cls    = (const float*)d_in[5];
  const float* pos    = (const float*)d_in[6];
  const float* ln1_w  = (const float*)d_in[7];
  const float* ln1_b  = (const float*)d_in[8];
  const float* qkv_w  = (const float*)d_in[9];
  const float* qkv_b  = (const float*)d_in[10];
  const float* proj_w = (const float*)d_in[11];
  const float* proj_b = (const float*)d_in[12];
  const float* ln2_w  = (const float*)d_in[13];
  const float* ln2_b  = (const float*)d_in[14];
  const float* fc1_w  = (const float*)d_in[15];
  const float* fc1_b  = (const float*)d_in[16];
  const float* fc2_w  = (const float*)d_in[17];
  const float* fc2_b  = (const float*)d_in[18];
  const float* norm_w = (const float*)d_in[19];
  const float* norm_b = (const float*)d_in[20];
  const float* head_w = (const float*)d_in[21];
  const float* head_b = (const float*)d_in[22];

  const size_t SQ = (size_t)D_ * 3 * D_, SP = (size_t)D_ * D_;
  const size_t S1 = (size_t)D_ * FF_, S2 = (size_t)FF_ * D_;
  const size_t WSET = SQ + SP + S1 + S2;

  float* ws = (float*)d_ws;
  int* idx = (int*)ws;                                   // 64 slots
  float4* gpart = (float4*)(ws + 64);                    // B*GSPLIT float4
  float* t = ws + 64 + 4 * B_ * GSPLIT;                  // B*T*D f32
  unsigned short* qkvb = (unsigned short*)(t + (size_t)B_ * T_ * D_);  // B*T*3D bf16
  unsigned short* hbuf = qkvb + (size_t)B_ * T_ * 3 * D_; // B*T*D bf16 (LN out)
  unsigned short* ob = hbuf + (size_t)B_ * T_ * D_;      // B*T*D bf16
  unsigned short* ub = ob + (size_t)B_ * T_ * D_;        // B*T*FF bf16
  unsigned short* xpb = ub + (size_t)B_ * T_ * FF_;      // B*196*768 bf16
  unsigned short* tpw = xpb + (size_t)B_ * NP_ * 768;    // E*384*768 bf16
  unsigned short* wbase = tpw + (size_t)E_ * D_ * 768;
  size_t fixed_bytes = (size_t)((char*)wbase - (char*)d_ws);
  bool hoist = ws_size >= fixed_bytes + WSET * 2ull * E_ * L_ + 4096;
  int NL = hoist ? L_ : 1;
  unsigned short* tq = wbase;
  unsigned short* tp = tq + (size_t)NL * E_ * SQ;
  unsigned short* t1 = tp + (size_t)NL * E_ * SP;
  unsigned short* t2 = t1 + (size_t)NL * E_ * S1;

  gate_partial<<<dim3(B_, GSPLIT), 256, 0, stream>>>(x, gate_w, gpart);
  gate_reduce<<<B_, 64, 0, stream>>>(gpart, gate_b, idx);
  cls_kernel<<<B_, D_, 0, stream>>>(cls, pos, idx, t);
  im2col_kernel<<<dim3(NP_, B_), 256, 0, stream>>>(x, xpb);
  ptrans_kernel<<<dim3(36, E_), 256, 0, stream>>>(patch_w, tpw);
  if (hoist)
    wtrans_kernel<<<dim3(216, E_, L_), 256, 0, stream>>>(qkv_w, proj_w, fc1_w, fc2_w,
                                                         tq, tp, t1, t2, 0);
  // patch embed GEMM: t[b][1..196] = xpb @ patch_w^T + patch_b + pos
  gemm_mfma<4, 32, 64><<<dim3(6, 7, B_), 256, 0, stream>>>(
      xpb, tpw, patch_b, t, idx, 0, 768, D_, NP_, (size_t)NP_ * 768, 1, pos);

  for (int l = 0; l < L_; ++l) {
    int slot = hoist ? l : 0;
    if (!hoist)
      wtrans_kernel<<<dim3(216, E_, 1), 256, 0, stream>>>(qkv_w, proj_w, fc1_w, fc2_w,
                                                          tq, tp, t1, t2, l);
    unsigned short* tql = tq + (size_t)slot * E_ * SQ;
    unsigned short* tpl = tp + (size_t)slot * E_ * SP;
    unsigned short* t1l = t1 + (size_t)slot * E_ * S1;
    unsigned short* t2l = t2 + (size_t)slot * E_ * S2;
    ln_kernel<<<dim3(50, B_), 256, 0, stream>>>(t, hbuf, ln1_w, ln1_b, idx, l);
    gemm_mfma<3, 64, 128><<<dim3(9, 4, B_), 256, 0, stream>>>(
        hbuf, tql, qkv_b, qkvb, idx, l, D_, 3 * D_, T_, (size_t)T_ * D_, L_, nullptr);
    attn_mfma<<<dim3(7, H_, B_), 128, 0, stream>>>(qkvb, ob);
    gemm_mfma<1, 32, 64><<<dim3(6, 7, B_), 256, 0, stream>>>(
        ob, tpl, proj_b, t, idx, l, D_, D_, T_, (size_t)T_ * D_, L_, nullptr);
    ln_kernel<<<dim3(50, B_), 256, 0, stream>>>(t, hbuf, ln2_w, ln2_b, idx, l);
    gemm_mfma<2, 64, 128><<<dim3(12, 4, B_), 256, 0, stream>>>(
        hbuf, t1l, fc1_b, ub, idx, l, D_, FF_, T_, (size_t)T_ * D_, L_, nullptr);
    gemm_mfma<1, 32, 64><<<dim3(6, 7, B_), 256, 0, stream>>>(
        ub, t2l, fc2_b, t, idx, l, FF_, D_, T_, (size_t)T_ * FF_, L_, nullptr);
  }
  head_kernel<<<B_, 64, 0, stream>>>(t, norm_w, norm_b, head_w, head_b, idx, (float*)d_out);
}

// Round 12
// 1267.136 us; speedup vs baseline: 1.2066x; 1.2066x over previous
//
#include <hip/hip_runtime.h>
#include <math.h>

#define E_ 4
#define B_ 16
#define S_ 224
#define P_ 16
#define D_ 384
#define H_ 6
#define HD_ 64
#define L_ 12
#define FF_ 1536
#define NC_ 10
#define NP_ 196
#define T_ 197
#define GATE_K (3 * S_ * S_)  // 150528
#define GSPLIT 32
#define GCHUNK (GATE_K / GSPLIT)  // 4704

typedef __attribute__((ext_vector_type(8))) short bf16x8;
typedef __attribute__((ext_vector_type(4))) float f32x4;

__device__ inline unsigned short f2bf(float f) {
  union { float f; unsigned u; } v; v.f = f;
  unsigned r = v.u + 0x7FFFu + ((v.u >> 16) & 1u);  // RNE
  return (unsigned short)(r >> 16);
}

// ---------------- gate phase 1: partial dot products ----------------
__global__ __launch_bounds__(256) void gate_partial(const float* __restrict__ x,
                                                    const float* __restrict__ gw,
                                                    float4* __restrict__ part) {
  int b = blockIdx.x, s = blockIdx.y, tid = threadIdx.x;
  const float* xb = x + (size_t)b * GATE_K;
  const float4* gw4 = (const float4*)gw;
  int i0 = s * GCHUNK, i1 = i0 + GCHUNK;
  float4 acc = make_float4(0.f, 0.f, 0.f, 0.f);
  for (int i = i0 + tid; i < i1; i += 256) {
    float xv = xb[i];
    float4 w = gw4[i];
    acc.x += xv * w.x; acc.y += xv * w.y; acc.z += xv * w.z; acc.w += xv * w.w;
  }
  __shared__ float4 red[256];
  red[tid] = acc;
  __syncthreads();
  for (int off = 128; off > 0; off >>= 1) {
    if (tid < off) {
      float4 o = red[tid + off];
      red[tid].x += o.x; red[tid].y += o.y; red[tid].z += o.z; red[tid].w += o.w;
    }
    __syncthreads();
  }
  if (tid == 0) part[b * GSPLIT + s] = red[0];
}

// ---------------- gate phase 2: reduce + argmax + cls row (merged) ----------------
__global__ void gate_reduce_cls(const float4* __restrict__ part, const float* __restrict__ gb,
                                const float* __restrict__ cls, const float* __restrict__ pos,
                                int* __restrict__ idx, float* __restrict__ t) {
  int b = blockIdx.x, tid = threadIdx.x;  // 384 threads
  __shared__ int eS;
  if (tid < 64) {
    float4 a = make_float4(0.f, 0.f, 0.f, 0.f);
    if (tid < GSPLIT) a = part[b * GSPLIT + tid];
#pragma unroll
    for (int off = 1; off < 64; off <<= 1) {
      a.x += __shfl_xor(a.x, off);
      a.y += __shfl_xor(a.y, off);
      a.z += __shfl_xor(a.z, off);
      a.w += __shfl_xor(a.w, off);
    }
    if (tid == 0) {
      float v[4] = {a.x + gb[0], a.y + gb[1], a.z + gb[2], a.w + gb[3]};
      int best = 0;
      for (int e = 1; e < 4; ++e) if (v[e] > v[best]) best = e;
      idx[b] = best;
      eS = best;
    }
  }
  __syncthreads();
  int e = eS;
  t[((size_t)b * T_) * D_ + tid] = cls[e * D_ + tid] + pos[((size_t)e * T_) * D_ + tid];
}

// ---------------- im2col: x fp32 -> xpb bf16 [B][196][768] ----------------
__global__ __launch_bounds__(256) void im2col_kernel(const float* __restrict__ x,
                                                     unsigned short* __restrict__ xpb) {
  int m = blockIdx.x, b = blockIdx.y, tid = threadIdx.x;
  int pr = m / 14, pc = m - pr * 14;
#pragma unroll
  for (int i = 0; i < 3; ++i) {
    int j = tid + i * 256;
    int c = j >> 8, y = (j >> 4) & 15, xx = j & 15;
    float v = x[(((size_t)b * 3 + c) * S_ + pr * 16 + y) * S_ + pc * 16 + xx];
    xpb[((size_t)b * NP_ + m) * 768 + j] = f2bf(v);
  }
}

// ---------------- transpose tile helper: XOR-swizzled, conflict-free ----------------
__device__ inline void trans_tile_64(const float* __restrict__ src, int srcN,
                                     unsigned short* __restrict__ dst, int dstK,
                                     int k0, int n0, int tid) {
  __shared__ unsigned short tile[64][64];
  int rr = tid >> 4, c4 = (tid & 15) * 4;
#pragma unroll
  for (int p = 0; p < 4; ++p) {
    int row = p * 16 + rr;
    float4 v = *(const float4*)(src + (size_t)(k0 + row) * srcN + n0 + c4);
    ushort4 o;
    o.x = f2bf(v.x); o.y = f2bf(v.y); o.z = f2bf(v.z); o.w = f2bf(v.w);
    *(ushort4*)&tile[row][c4 ^ (row & 56)] = o;
  }
  __syncthreads();
  int n = tid >> 3, k8 = (tid & 7) * 8;
#pragma unroll
  for (int p = 0; p < 2; ++p) {
    int nn = p * 32 + n;
    union { unsigned short us[8]; uint4 u4; } o;
#pragma unroll
    for (int j = 0; j < 8; ++j) {
      int row = k8 + j;
      o.us[j] = tile[row][nn ^ (row & 56)];
    }
    *(uint4*)(dst + (size_t)(n0 + nn) * dstK + k0 + k8) = o.u4;
  }
}

// ---------------- patch_w transpose ----------------
__global__ __launch_bounds__(256) void ptrans_kernel(const float* __restrict__ pw,
                                                     unsigned short* __restrict__ tpw) {
  int e = blockIdx.y;
  int r = blockIdx.x;  // 72 tiles
  const int K = 768, N = 384;
  int kt = r / 6, nt = r - kt * 6;
  trans_tile_64(pw + (size_t)e * K * N, N, tpw + (size_t)e * N * K, K,
                kt * 64, nt * 64, threadIdx.x);
}

// ---------------- weight transpose ----------------
__global__ __launch_bounds__(256) void wtrans_kernel(
    const float* __restrict__ qw, const float* __restrict__ pw,
    const float* __restrict__ f1, const float* __restrict__ f2,
    unsigned short* __restrict__ tq, unsigned short* __restrict__ tp,
    unsigned short* __restrict__ t1, unsigned short* __restrict__ t2, int lsrc_base) {
  int e = blockIdx.y;
  int slot = blockIdx.z;
  int l = lsrc_base + slot;
  int r = blockIdx.x;  // 0..431
  const float* src; unsigned short* dst; int K, N, kt, nt;
  if (r < 108) {        // qkv
    K = 384; N = 1152;
    src = qw + (size_t)(e * L_ + l) * K * N; dst = tq + (size_t)(slot * E_ + e) * K * N;
    kt = r / 18; nt = r % 18;
  } else if (r < 144) { // proj
    r -= 108; K = 384; N = 384;
    src = pw + (size_t)(e * L_ + l) * K * N; dst = tp + (size_t)(slot * E_ + e) * K * N;
    kt = r / 6; nt = r % 6;
  } else if (r < 288) { // fc1
    r -= 144; K = 384; N = 1536;
    src = f1 + (size_t)(e * L_ + l) * K * N; dst = t1 + (size_t)(slot * E_ + e) * K * N;
    kt = r / 24; nt = r % 24;
  } else {              // fc2
    r -= 288; K = 1536; N = 384;
    src = f2 + (size_t)(e * L_ + l) * K * N; dst = t2 + (size_t)(slot * E_ + e) * K * N;
    kt = r / 6; nt = r % 6;
  }
  trans_tile_64(src, N, dst, K, kt * 64, nt * 64, threadIdx.x);
}

// ---------------- layernorm -> bf16 out ----------------
__global__ void ln_kernel(const float* __restrict__ in, unsigned short* __restrict__ out,
                          const float* __restrict__ w, const float* __restrict__ bc,
                          const int* __restrict__ idx, int l) {
  int b = blockIdx.y;
  int row = blockIdx.x * 4 + (threadIdx.x >> 6);
  if (row >= T_) return;
  int lane = threadIdx.x & 63;
  int e = idx[b];
  const float* rp = in + ((size_t)b * T_ + row) * D_;
  float v[6];
  float s = 0.f;
#pragma unroll
  for (int j = 0; j < 6; ++j) { v[j] = rp[lane + j * 64]; s += v[j]; }
#pragma unroll
  for (int off = 1; off < 64; off <<= 1) s += __shfl_xor(s, off);
  float mean = s * (1.f / 384.f);
  float sq = 0.f;
#pragma unroll
  for (int j = 0; j < 6; ++j) { float dd = v[j] - mean; sq += dd * dd; }
#pragma unroll
  for (int off = 1; off < 64; off <<= 1) sq += __shfl_xor(sq, off);
  float rs = rsqrtf(sq * (1.f / 384.f) + 1e-6f);
  const float* wrow = w + ((size_t)e * L_ + l) * D_;
  const float* brow = bc + ((size_t)e * L_ + l) * D_;
  unsigned short* op = out + ((size_t)b * T_ + row) * D_;
#pragma unroll
  for (int j = 0; j < 6; ++j) {
    int d = lane + j * 64;
    op[d] = f2bf((v[j] - mean) * rs * wrow[d] + brow[d]);
  }
}

// ---------------- MFMA bf16 GEMM, 64x64 tile, BK=64 ----------------
// EPI: 0 fp32 store, 1 fp32 residual add, 2 GELU->bf16, 3 bf16 store,
//      4 patch: fp32 t store at row+1 with pos add.
template <int EPI>
__global__ __launch_bounds__(256, 4) void gemm_mfma(
    const unsigned short* __restrict__ A, const unsigned short* __restrict__ WT,
    const float* __restrict__ bias, void* __restrict__ Out,
    const int* __restrict__ idx, int l, int K, int N, int M, size_t asb,
    int bstride, const float* __restrict__ pos) {
  int b = blockIdx.z;
  int e = idx[b];
  int n0 = blockIdx.x * 64, m0 = blockIdx.y * 64;
  int tid = threadIdx.x;
  const unsigned short* Ab = A + (size_t)b * asb;
  const unsigned short* Wb = WT + (size_t)e * N * K;
  __shared__ unsigned short Asl[8][64][8];
  __shared__ unsigned short Bsl[8][64][8];
  f32x4 acc[2][2];
#pragma unroll
  for (int i = 0; i < 2; ++i)
#pragma unroll
    for (int j = 0; j < 2; ++j) acc[i][j] = (f32x4){0.f, 0.f, 0.f, 0.f};
  int wid = tid >> 6, lane = tid & 63;
  int wm = (wid >> 1) * 32, wn = (wid & 1) * 32;
  int lrow = lane & 15, lk = lane >> 4;
  int ar = tid >> 2, akq = tid & 3;
  for (int k0 = 0; k0 < K; k0 += 64) {
    uint4 av0 = make_uint4(0, 0, 0, 0), av1 = av0;
    if (m0 + ar < M) {
      const unsigned short* ap = Ab + (size_t)(m0 + ar) * K + k0 + akq * 8;
      av0 = *(const uint4*)(ap);
      av1 = *(const uint4*)(ap + 32);
    }
    const unsigned short* bp = Wb + (size_t)(n0 + ar) * K + k0 + akq * 8;
    uint4 bv0 = *(const uint4*)(bp);
    uint4 bv1 = *(const uint4*)(bp + 32);
    __syncthreads();
    *(uint4*)&Asl[akq][ar][0] = av0;
    *(uint4*)&Asl[akq + 4][ar][0] = av1;
    *(uint4*)&Bsl[akq][ar][0] = bv0;
    *(uint4*)&Bsl[akq + 4][ar][0] = bv1;
    __syncthreads();
#pragma unroll
    for (int ks = 0; ks < 2; ++ks) {
      bf16x8 a0 = *(const bf16x8*)&Asl[ks * 4 + lk][wm + lrow][0];
      bf16x8 a1 = *(const bf16x8*)&Asl[ks * 4 + lk][wm + 16 + lrow][0];
      bf16x8 b0 = *(const bf16x8*)&Bsl[ks * 4 + lk][wn + lrow][0];
      bf16x8 b1 = *(const bf16x8*)&Bsl[ks * 4 + lk][wn + 16 + lrow][0];
      acc[0][0] = __builtin_amdgcn_mfma_f32_16x16x32_bf16(a0, b0, acc[0][0], 0, 0, 0);
      acc[0][1] = __builtin_amdgcn_mfma_f32_16x16x32_bf16(a0, b1, acc[0][1], 0, 0, 0);
      acc[1][0] = __builtin_amdgcn_mfma_f32_16x16x32_bf16(a1, b0, acc[1][0], 0, 0, 0);
      acc[1][1] = __builtin_amdgcn_mfma_f32_16x16x32_bf16(a1, b1, acc[1][1], 0, 0, 0);
    }
  }
  const float* brow = bias + ((size_t)e * bstride + l) * N + n0;
#pragma unroll
  for (int fm = 0; fm < 2; ++fm)
#pragma unroll
    for (int fn = 0; fn < 2; ++fn) {
      int col = wn + fn * 16 + lrow;
      float bval = brow[col];
#pragma unroll
      for (int r = 0; r < 4; ++r) {
        int row = m0 + wm + fm * 16 + lk * 4 + r;
        if (row >= M) continue;
        float val = acc[fm][fn][r] + bval;
        if (EPI == 0) {
          ((float*)Out)[((size_t)b * T_ + row) * N + n0 + col] = val;
        } else if (EPI == 1) {
          float* p = (float*)Out + ((size_t)b * T_ + row) * N + n0 + col;
          *p = *p + val;
        } else if (EPI == 2) {
          val = 0.5f * val * (1.f + erff(val * 0.70710678118654752f));
          ((unsigned short*)Out)[((size_t)b * T_ + row) * N + n0 + col] = f2bf(val);
        } else if (EPI == 3) {
          ((unsigned short*)Out)[((size_t)b * T_ + row) * N + n0 + col] = f2bf(val);
        } else {  // 4: patch -> t rows 1..196 with pos
          ((float*)Out)[((size_t)b * T_ + 1 + row) * N + n0 + col] =
              val + pos[((size_t)e * T_ + 1 + row) * N + n0 + col];
        }
      }
    }
}

// ---------------- attention: MFMA bf16, 2 waves/block ----------------
__global__ __launch_bounds__(128, 2) void attn_mfma(const unsigned short* __restrict__ qkvb,
                                                    unsigned short* __restrict__ ob) {
  int b = blockIdx.z, h = blockIdx.y, qt = blockIdx.x;
  int tid = threadIdx.x;  // 128
  int w = tid >> 6, lane = tid & 63;
  int q0 = qt * 32 + w * 16;
  __shared__ unsigned short Vt[64][232];
  __shared__ unsigned short Pl[2][16][232];
  const unsigned short* base = qkvb + (size_t)b * T_ * (3 * D_) + h * HD_;

  {
    int d2 = (tid & 31) * 2;
    int kvh = tid >> 5;  // 0..3
    const unsigned short* vb = base + 2 * D_;
    for (int i = 0; i < 56; ++i) {
      int kv = kvh * 56 + i;
      int kvc = kv < T_ ? kv : T_ - 1;
      unsigned int vv = *(const unsigned int*)(vb + (size_t)kvc * (3 * D_) + d2);
      Vt[d2][kv] = (unsigned short)(vv & 0xffffu);
      Vt[d2 + 1][kv] = (unsigned short)(vv >> 16);
    }
  }

  int c16 = lane & 15, g4 = lane >> 4;

  int qrow = q0 + c16; if (qrow > T_ - 1) qrow = T_ - 1;
  bf16x8 aq[2];
#pragma unroll
  for (int ks = 0; ks < 2; ++ks)
    aq[ks] = *(const bf16x8*)(base + (size_t)qrow * (3 * D_) + ks * 32 + g4 * 8);

  f32x4 sc[14];
#pragma unroll
  for (int nf = 0; nf < 14; ++nf) sc[nf] = (f32x4){0.f, 0.f, 0.f, 0.f};
  const unsigned short* kb = base + D_;
#pragma unroll
  for (int nf = 0; nf < 14; ++nf) {
    int krow = nf * 16 + c16; if (krow > T_ - 1) krow = T_ - 1;
#pragma unroll
    for (int ks = 0; ks < 2; ++ks) {
      bf16x8 bk = *(const bf16x8*)(kb + (size_t)krow * (3 * D_) + ks * 32 + g4 * 8);
      sc[nf] = __builtin_amdgcn_mfma_f32_16x16x32_bf16(aq[ks], bk, sc[nf], 0, 0, 0);
    }
  }

  float mx[4], sm[4];
#pragma unroll
  for (int r = 0; r < 4; ++r) mx[r] = -1e30f;
#pragma unroll
  for (int nf = 0; nf < 14; ++nf) {
    bool valid = (nf * 16 + c16) < T_;
#pragma unroll
    for (int r = 0; r < 4; ++r) {
      float s = valid ? sc[nf][r] * 0.125f : -1e30f;
      sc[nf][r] = s;
      mx[r] = fmaxf(mx[r], s);
    }
  }
#pragma unroll
  for (int r = 0; r < 4; ++r) {
#pragma unroll
    for (int off = 1; off < 16; off <<= 1) mx[r] = fmaxf(mx[r], __shfl_xor(mx[r], off, 16));
    sm[r] = 0.f;
  }
#pragma unroll
  for (int nf = 0; nf < 14; ++nf)
#pragma unroll
    for (int r = 0; r < 4; ++r) {
      float p = __expf(sc[nf][r] - mx[r]);
      sc[nf][r] = p;
      sm[r] += p;
    }
#pragma unroll
  for (int r = 0; r < 4; ++r) {
#pragma unroll
    for (int off = 1; off < 16; off <<= 1) sm[r] += __shfl_xor(sm[r], off, 16);
    sm[r] = 1.f / sm[r];
  }
#pragma unroll
  for (int nf = 0; nf < 14; ++nf) {
    int col = nf * 16 + c16;
#pragma unroll
    for (int r = 0; r < 4; ++r)
      Pl[w][g4 * 4 + r][col] = f2bf(sc[nf][r] * sm[r]);
  }
  __syncthreads();

  f32x4 oacc[4];
#pragma unroll
  for (int nf = 0; nf < 4; ++nf) oacc[nf] = (f32x4){0.f, 0.f, 0.f, 0.f};
#pragma unroll
  for (int ks = 0; ks < 7; ++ks) {
    bf16x8 ap = *(const bf16x8*)&Pl[w][c16][ks * 32 + g4 * 8];
#pragma unroll
    for (int nf = 0; nf < 4; ++nf) {
      bf16x8 bv = *(const bf16x8*)&Vt[nf * 16 + c16][ks * 32 + g4 * 8];
      oacc[nf] = __builtin_amdgcn_mfma_f32_16x16x32_bf16(ap, bv, oacc[nf], 0, 0, 0);
    }
  }

#pragma unroll
  for (int nf = 0; nf < 4; ++nf) {
    int d = nf * 16 + c16;
#pragma unroll
    for (int r = 0; r < 4; ++r) {
      int q = q0 + g4 * 4 + r;
      if (q < T_)
        ob[((size_t)b * T_ + q) * D_ + h * HD_ + d] = f2bf(oacc[nf][r]);
    }
  }
}

// ---------------- final LN(row 0) + head ----------------
__global__ void head_kernel(const float* __restrict__ t, const float* __restrict__ nw,
                            const float* __restrict__ nb, const float* __restrict__ hw,
                            const float* __restrict__ hb, const int* __restrict__ idx,
                            float* __restrict__ out) {
  int b = blockIdx.x;
  int e = idx[b];
  int lane = threadIdx.x;  // 64
  const float* rp = t + (size_t)b * T_ * D_;
  float v[6];
  float s = 0.f;
#pragma unroll
  for (int j = 0; j < 6; ++j) { v[j] = rp[lane + j * 64]; s += v[j]; }
#pragma unroll
  for (int off = 1; off < 64; off <<= 1) s += __shfl_xor(s, off);
  float mean = s * (1.f / 384.f);
  float sq = 0.f;
#pragma unroll
  for (int j = 0; j < 6; ++j) { float dd = v[j] - mean; sq += dd * dd; }
#pragma unroll
  for (int off = 1; off < 64; off <<= 1) sq += __shfl_xor(sq, off);
  float rs = rsqrtf(sq * (1.f / 384.f) + 1e-6f);
  __shared__ float ln[D_];
#pragma unroll
  for (int j = 0; j < 6; ++j) {
    int d = lane + j * 64;
    ln[d] = (v[j] - mean) * rs * nw[e * D_ + d] + nb[e * D_ + d];
  }
  __syncthreads();
  if (lane < NC_) {
    float acc = hb[e * NC_ + lane];
    for (int d = 0; d < D_; ++d) acc += ln[d] * hw[((size_t)e * D_ + d) * NC_ + lane];
    out[b * NC_ + lane] = acc;
  }
}

extern "C" void kernel_launch(void* const* d_in, const int* in_sizes, int n_in,
                              void* d_out, int out_size, void* d_ws, size_t ws_size,
                              hipStream_t stream) {
  const float* x      = (const float*)d_in[0];
  const float* gate_w = (const float*)d_in[1];
  const float* gate_b = (const float*)d_in[2];
  const float* patch_w = (const float*)d_in[3];
  const float* patch_b = (const float*)d_in[4];
  const float* cls    = (const float*)d_in[5];
  const float* pos    = (const float*)d_in[6];
  const float* ln1_w  = (const float*)d_in[7];
  const float* ln1_b  = (const float*)d_in[8];
  const float* qkv_w  = (const float*)d_in[9];
  const float* qkv_b  = (const float*)d_in[10];
  const float* proj_w = (const float*)d_in[11];
  const float* proj_b = (const float*)d_in[12];
  const float* ln2_w  = (const float*)d_in[13];
  const float* ln2_b  = (const float*)d_in[14];
  const float* fc1_w  = (const float*)d_in[15];
  const float* fc1_b  = (const float*)d_in[16];
  const float* fc2_w  = (const float*)d_in[17];
  const float* fc2_b  = (const float*)d_in[18];
  const float* norm_w = (const float*)d_in[19];
  const float* norm_b = (const float*)d_in[20];
  const float* head_w = (const float*)d_in[21];
  const float* head_b = (const float*)d_in[22];

  const size_t SQ = (size_t)D_ * 3 * D_, SP = (size_t)D_ * D_;
  const size_t S1 = (size_t)D_ * FF_, S2 = (size_t)FF_ * D_;
  const size_t WSET = SQ + SP + S1 + S2;

  float* ws = (float*)d_ws;
  int* idx = (int*)ws;                                   // 64 slots
  float4* gpart = (float4*)(ws + 64);                    // B*GSPLIT float4
  float* t = ws + 64 + 4 * B_ * GSPLIT;                  // B*T*D f32
  unsigned short* qkvb = (unsigned short*)(t + (size_t)B_ * T_ * D_);  // B*T*3D bf16
  unsigned short* hbuf = qkvb + (size_t)B_ * T_ * 3 * D_; // B*T*D bf16 (LN out)
  unsigned short* ob = hbuf + (size_t)B_ * T_ * D_;      // B*T*D bf16
  unsigned short* ub = ob + (size_t)B_ * T_ * D_;        // B*T*FF bf16
  unsigned short* xpb = ub + (size_t)B_ * T_ * FF_;      // B*196*768 bf16
  unsigned short* tpw = xpb + (size_t)B_ * NP_ * 768;    // E*384*768 bf16
  unsigned short* wbase = tpw + (size_t)E_ * D_ * 768;
  size_t fixed_bytes = (size_t)((char*)wbase - (char*)d_ws);
  bool hoist = ws_size >= fixed_bytes + WSET * 2ull * E_ * L_ + 4096;
  int NL = hoist ? L_ : 1;
  unsigned short* tq = wbase;
  unsigned short* tp = tq + (size_t)NL * E_ * SQ;
  unsigned short* t1 = tp + (size_t)NL * E_ * SP;
  unsigned short* t2 = t1 + (size_t)NL * E_ * S1;

  gate_partial<<<dim3(B_, GSPLIT), 256, 0, stream>>>(x, gate_w, gpart);
  gate_reduce_cls<<<B_, D_, 0, stream>>>(gpart, gate_b, cls, pos, idx, t);
  im2col_kernel<<<dim3(NP_, B_), 256, 0, stream>>>(x, xpb);
  ptrans_kernel<<<dim3(72, E_), 256, 0, stream>>>(patch_w, tpw);
  if (hoist)
    wtrans_kernel<<<dim3(432, E_, L_), 256, 0, stream>>>(qkv_w, proj_w, fc1_w, fc2_w,
                                                         tq, tp, t1, t2, 0);
  // patch embed GEMM: t[b][1..196] = xpb @ patch_w^T + patch_b + pos
  gemm_mfma<4><<<dim3(6, 4, B_), 256, 0, stream>>>(
      xpb, tpw, patch_b, t, idx, 0, 768, D_, NP_, (size_t)NP_ * 768, 1, pos);

  for (int l = 0; l < L_; ++l) {
    int slot = hoist ? l : 0;
    if (!hoist)
      wtrans_kernel<<<dim3(432, E_, 1), 256, 0, stream>>>(qkv_w, proj_w, fc1_w, fc2_w,
                                                          tq, tp, t1, t2, l);
    unsigned short* tql = tq + (size_t)slot * E_ * SQ;
    unsigned short* tpl = tp + (size_t)slot * E_ * SP;
    unsigned short* t1l = t1 + (size_t)slot * E_ * S1;
    unsigned short* t2l = t2 + (size_t)slot * E_ * S2;
    ln_kernel<<<dim3(50, B_), 256, 0, stream>>>(t, hbuf, ln1_w, ln1_b, idx, l);
    gemm_mfma<3><<<dim3(18, 4, B_), 256, 0, stream>>>(
        hbuf, tql, qkv_b, qkvb, idx, l, D_, 3 * D_, T_, (size_t)T_ * D_, L_, nullptr);
    attn_mfma<<<dim3(7, H_, B_), 128, 0, stream>>>(qkvb, ob);
    gemm_mfma<1><<<dim3(6, 4, B_), 256, 0, stream>>>(
        ob, tpl, proj_b, t, idx, l, D_, D_, T_, (size_t)T_ * D_, L_, nullptr);
    ln_kernel<<<dim3(50, B_), 256, 0, stream>>>(t, hbuf, ln2_w, ln2_b, idx, l);
    gemm_mfma<2><<<dim3(24, 4, B_), 256, 0, stream>>>(
        hbuf, t1l, fc1_b, ub, idx, l, D_, FF_, T_, (size_t)T_ * D_, L_, nullptr);
    gemm_mfma<1><<<dim3(6, 4, B_), 256, 0, stream>>>(
        ub, t2l, fc2_b, t, idx, l, FF_, D_, T_, (size_t)T_ * FF_, L_, nullptr);
  }
  head_kernel<<<B_, 64, 0, stream>>>(t, norm_w, norm_b, head_w, head_b, idx, (float*)d_out);
}